// Round 2
// baseline (1177.974 us; speedup 1.0000x reference)
//
#include <hip/hip_runtime.h>
#include <math.h>

#define N_NODES 50000
#define N_EDGES 1600000
#define IN_CH   512
#define OUT_CH  48

// ---------------- Kernel 1: xw = features @ weight ----------------
// One thread per (row, 4-column group). 50000 * 12 = 600000 threads.
// features row read as float4 (broadcast across the 12 threads of a row via L1),
// weight read as float4, coalesced across adjacent threads (consecutive cg).
__global__ void gemm_xw(const float* __restrict__ f,
                        const float* __restrict__ w,
                        float* __restrict__ xw) {
    int idx = blockIdx.x * blockDim.x + threadIdx.x;
    const int total = N_NODES * (OUT_CH / 4);
    if (idx >= total) return;
    int row = idx / (OUT_CH / 4);
    int cg  = idx % (OUT_CH / 4);

    const float4* f4 = reinterpret_cast<const float4*>(f + (size_t)row * IN_CH);
    const float*  wc = w + cg * 4;

    float4 acc = make_float4(0.f, 0.f, 0.f, 0.f);
    #pragma unroll 4
    for (int k4 = 0; k4 < IN_CH / 4; ++k4) {
        float4 fv = f4[k4];
        float4 w0 = *reinterpret_cast<const float4*>(wc + (size_t)(4 * k4 + 0) * OUT_CH);
        float4 w1 = *reinterpret_cast<const float4*>(wc + (size_t)(4 * k4 + 1) * OUT_CH);
        float4 w2 = *reinterpret_cast<const float4*>(wc + (size_t)(4 * k4 + 2) * OUT_CH);
        float4 w3 = *reinterpret_cast<const float4*>(wc + (size_t)(4 * k4 + 3) * OUT_CH);
        acc.x = fmaf(fv.x, w0.x, acc.x); acc.y = fmaf(fv.x, w0.y, acc.y);
        acc.z = fmaf(fv.x, w0.z, acc.z); acc.w = fmaf(fv.x, w0.w, acc.w);
        acc.x = fmaf(fv.y, w1.x, acc.x); acc.y = fmaf(fv.y, w1.y, acc.y);
        acc.z = fmaf(fv.y, w1.z, acc.z); acc.w = fmaf(fv.y, w1.w, acc.w);
        acc.x = fmaf(fv.z, w2.x, acc.x); acc.y = fmaf(fv.z, w2.y, acc.y);
        acc.z = fmaf(fv.z, w2.z, acc.z); acc.w = fmaf(fv.z, w2.w, acc.w);
        acc.x = fmaf(fv.w, w3.x, acc.x); acc.y = fmaf(fv.w, w3.y, acc.y);
        acc.z = fmaf(fv.w, w3.z, acc.z); acc.w = fmaf(fv.w, w3.w, acc.w);
    }
    *reinterpret_cast<float4*>(xw + (size_t)row * OUT_CH + cg * 4) = acc;
}

// ---------------- Kernel 2: scatter-add messages into d_out ----------------
// One thread per (edge, 4-column group). For a fixed edge, its 12 threads read
// a contiguous 192B row of xw (coalesced) and atomically add into a contiguous
// 192B row of aggr.
__global__ void scatter_add(const int* __restrict__ src,
                            const int* __restrict__ dst,
                            const float* __restrict__ ew,
                            const float* __restrict__ xw,
                            float* __restrict__ aggr) {
    int idx = blockIdx.x * blockDim.x + threadIdx.x;
    const int total = N_EDGES * (OUT_CH / 4);
    if (idx >= total) return;
    int e  = idx / (OUT_CH / 4);
    int cg = idx % (OUT_CH / 4);

    int s = src[e];
    int d = dst[e];
    float wgt = ew[e];

    float4 v = *reinterpret_cast<const float4*>(xw + (size_t)s * OUT_CH + cg * 4);
    float* o = aggr + (size_t)d * OUT_CH + cg * 4;
    atomicAdd(o + 0, wgt * v.x);
    atomicAdd(o + 1, wgt * v.y);
    atomicAdd(o + 2, wgt * v.z);
    atomicAdd(o + 3, wgt * v.w);
}

// ---------------- Kernel 3: z = aggr + bias; out = log_softmax(z) ----------------
// One thread per row, in-place on d_out.
__global__ void log_softmax_rows(float* __restrict__ z,
                                 const float* __restrict__ bias) {
    int row = blockIdx.x * blockDim.x + threadIdx.x;
    if (row >= N_NODES) return;

    float v[OUT_CH];
    float4* zp = reinterpret_cast<float4*>(z + (size_t)row * OUT_CH);
    const float4* bp = reinterpret_cast<const float4*>(bias);

    float m = -INFINITY;
    #pragma unroll
    for (int g = 0; g < OUT_CH / 4; ++g) {
        float4 t = zp[g];
        float4 b = bp[g];
        t.x += b.x; t.y += b.y; t.z += b.z; t.w += b.w;
        v[4 * g + 0] = t.x; v[4 * g + 1] = t.y;
        v[4 * g + 2] = t.z; v[4 * g + 3] = t.w;
        m = fmaxf(m, fmaxf(fmaxf(t.x, t.y), fmaxf(t.z, t.w)));
    }
    float s = 0.f;
    #pragma unroll
    for (int c = 0; c < OUT_CH; ++c) s += expf(v[c] - m);
    float lse = logf(s) + m;
    #pragma unroll
    for (int g = 0; g < OUT_CH / 4; ++g) {
        float4 t;
        t.x = v[4 * g + 0] - lse; t.y = v[4 * g + 1] - lse;
        t.z = v[4 * g + 2] - lse; t.w = v[4 * g + 3] - lse;
        zp[g] = t;
    }
}

extern "C" void kernel_launch(void* const* d_in, const int* in_sizes, int n_in,
                              void* d_out, int out_size, void* d_ws, size_t ws_size,
                              hipStream_t stream) {
    // Inputs (setup_inputs order): edge_index [2,E] int, features [N,512] f32,
    // edge_weights [E] f32, weight [512,48] f32, bias [48] f32.
    const int*   edge_index = (const int*)d_in[0];
    const float* features   = (const float*)d_in[1];
    const float* eweights   = (const float*)d_in[2];
    const float* weight     = (const float*)d_in[3];
    const float* bias       = (const float*)d_in[4];

    const int* src = edge_index;            // edge_index[0, :]
    const int* dst = edge_index + N_EDGES;  // edge_index[1, :]

    float* out = (float*)d_out;             // [N, 48] — used as the aggregation buffer
    float* xw  = (float*)d_ws;              // [N, 48] projected features

    // Zero the aggregation buffer (harness poisons d_out; atomics need zeros).
    hipMemsetAsync(d_out, 0, (size_t)N_NODES * OUT_CH * sizeof(float), stream);

    // 1) xw = features @ weight
    {
        int total = N_NODES * (OUT_CH / 4);
        int block = 256;
        int grid  = (total + block - 1) / block;
        gemm_xw<<<grid, block, 0, stream>>>(features, weight, xw);
    }
    // 2) scatter-add weighted messages
    {
        int total = N_EDGES * (OUT_CH / 4);
        int block = 256;
        int grid  = (total + block - 1) / block;
        scatter_add<<<grid, block, 0, stream>>>(src, dst, eweights, xw, out);
    }
    // 3) bias + log_softmax, in place
    {
        int block = 256;
        int grid  = (N_NODES + block - 1) / block;
        log_softmax_rows<<<grid, block, 0, stream>>>(out, bias);
    }
}

// Round 3
// 582.707 us; speedup vs baseline: 2.0216x; 2.0216x over previous
//
#include <hip/hip_runtime.h>
#include <math.h>

#define N_NODES 50000
#define N_EDGES 1600000
#define IN_CH   512
#define OUT_CH  48

// ---------------- Kernel 1: xw = features @ weight ----------------
// (unchanged this round; known L1-bound, next target)
__global__ void gemm_xw(const float* __restrict__ f,
                        const float* __restrict__ w,
                        float* __restrict__ xw) {
    int idx = blockIdx.x * blockDim.x + threadIdx.x;
    const int total = N_NODES * (OUT_CH / 4);
    if (idx >= total) return;
    int row = idx / (OUT_CH / 4);
    int cg  = idx % (OUT_CH / 4);

    const float4* f4 = reinterpret_cast<const float4*>(f + (size_t)row * IN_CH);
    const float*  wc = w + cg * 4;

    float4 acc = make_float4(0.f, 0.f, 0.f, 0.f);
    #pragma unroll 4
    for (int k4 = 0; k4 < IN_CH / 4; ++k4) {
        float4 fv = f4[k4];
        float4 w0 = *reinterpret_cast<const float4*>(wc + (size_t)(4 * k4 + 0) * OUT_CH);
        float4 w1 = *reinterpret_cast<const float4*>(wc + (size_t)(4 * k4 + 1) * OUT_CH);
        float4 w2 = *reinterpret_cast<const float4*>(wc + (size_t)(4 * k4 + 2) * OUT_CH);
        float4 w3 = *reinterpret_cast<const float4*>(wc + (size_t)(4 * k4 + 3) * OUT_CH);
        acc.x = fmaf(fv.x, w0.x, acc.x); acc.y = fmaf(fv.x, w0.y, acc.y);
        acc.z = fmaf(fv.x, w0.z, acc.z); acc.w = fmaf(fv.x, w0.w, acc.w);
        acc.x = fmaf(fv.y, w1.x, acc.x); acc.y = fmaf(fv.y, w1.y, acc.y);
        acc.z = fmaf(fv.y, w1.z, acc.z); acc.w = fmaf(fv.y, w1.w, acc.w);
        acc.x = fmaf(fv.z, w2.x, acc.x); acc.y = fmaf(fv.z, w2.y, acc.y);
        acc.z = fmaf(fv.z, w2.z, acc.z); acc.w = fmaf(fv.z, w2.w, acc.w);
        acc.x = fmaf(fv.w, w3.x, acc.x); acc.y = fmaf(fv.w, w3.y, acc.y);
        acc.z = fmaf(fv.w, w3.z, acc.z); acc.w = fmaf(fv.w, w3.w, acc.w);
    }
    *reinterpret_cast<float4*>(xw + (size_t)row * OUT_CH + cg * 4) = acc;
}

// ---------------- CSR build: histogram of dst ----------------
__global__ void hist_dst(const int* __restrict__ dst, int* __restrict__ counts) {
    int e = blockIdx.x * blockDim.x + threadIdx.x;
    if (e < N_EDGES) atomicAdd(&counts[dst[e]], 1);
}

// ---------------- CSR build: exclusive scan (single block) ----------------
__global__ void scan_offsets(const int* __restrict__ counts,
                             int* __restrict__ offsets,
                             int* __restrict__ cursor) {
    __shared__ int part[1024];
    int t = threadIdx.x;
    const int CH = (N_NODES + 1023) / 1024;  // 49 per thread
    int lo = t * CH;
    int hi = lo + CH; if (hi > N_NODES) hi = N_NODES;

    int s = 0;
    for (int i = lo; i < hi; ++i) s += counts[i];
    part[t] = s;
    __syncthreads();
    // Hillis-Steele inclusive scan over 1024 partials
    for (int d = 1; d < 1024; d <<= 1) {
        int v = (t >= d) ? part[t - d] : 0;
        __syncthreads();
        part[t] += v;
        __syncthreads();
    }
    int run = (t == 0) ? 0 : part[t - 1];
    for (int i = lo; i < hi; ++i) {
        offsets[i] = run;
        cursor[i]  = run;
        run += counts[i];
    }
}

// ---------------- CSR build: permute (src, w) into dst-buckets ----------------
__global__ void build_perm(const int* __restrict__ src, const int* __restrict__ dst,
                           const float* __restrict__ ew, int* __restrict__ cursor,
                           int* __restrict__ s_src, float* __restrict__ s_w) {
    int e = blockIdx.x * blockDim.x + threadIdx.x;
    if (e >= N_EDGES) return;
    int d = dst[e];
    int pos = atomicAdd(&cursor[d], 1);
    s_src[pos] = src[e];
    s_w[pos]   = ew[e];
}

// ---------------- Fused gather-aggregate + bias + log-softmax ----------------
// One wave (64 lanes) per destination node; lane = output channel (48 active).
__global__ void aggregate_lsm(const int* __restrict__ counts,
                              const int* __restrict__ offsets,
                              const int* __restrict__ s_src,
                              const float* __restrict__ s_w,
                              const float* __restrict__ xw,
                              const float* __restrict__ bias,
                              float* __restrict__ out) {
    int node = (blockIdx.x * blockDim.x + threadIdx.x) >> 6;
    int lane = threadIdx.x & 63;
    if (node >= N_NODES) return;

    int off = offsets[node];
    int cnt = counts[node];

    float acc = 0.f;
    if (lane < OUT_CH) {
        int k = 0;
        for (; k + 2 <= cnt; k += 2) {
            int   s0 = s_src[off + k],     s1 = s_src[off + k + 1];
            float w0 = s_w[off + k],       w1 = s_w[off + k + 1];
            float x0 = xw[(size_t)s0 * OUT_CH + lane];
            float x1 = xw[(size_t)s1 * OUT_CH + lane];
            acc = fmaf(w0, x0, acc);
            acc = fmaf(w1, x1, acc);
        }
        if (k < cnt) {
            int   s0 = s_src[off + k];
            float w0 = s_w[off + k];
            acc = fmaf(w0, xw[(size_t)s0 * OUT_CH + lane], acc);
        }
        acc += bias[lane];
    }

    float z = (lane < OUT_CH) ? acc : -INFINITY;
    float m = z;
    #pragma unroll
    for (int d = 32; d >= 1; d >>= 1) m = fmaxf(m, __shfl_xor(m, d));
    float e = (lane < OUT_CH) ? expf(z - m) : 0.f;
    float s = e;
    #pragma unroll
    for (int d = 32; d >= 1; d >>= 1) s += __shfl_xor(s, d);
    float lse = m + logf(s);

    if (lane < OUT_CH) out[(size_t)node * OUT_CH + lane] = z - lse;
}

extern "C" void kernel_launch(void* const* d_in, const int* in_sizes, int n_in,
                              void* d_out, int out_size, void* d_ws, size_t ws_size,
                              hipStream_t stream) {
    const int*   edge_index = (const int*)d_in[0];
    const float* features   = (const float*)d_in[1];
    const float* eweights   = (const float*)d_in[2];
    const float* weight     = (const float*)d_in[3];
    const float* bias       = (const float*)d_in[4];

    const int* src = edge_index;            // edge_index[0, :]
    const int* dst = edge_index + N_EDGES;  // edge_index[1, :]

    float* out = (float*)d_out;

    // Workspace layout (bytes):
    //   xw      @ 0          : 50000*48*4 = 9,600,000
    //   counts  @ 9,600,000  : 200,000
    //   offsets @ 9,800,000  : 200,000
    //   cursor  @ 10,000,000 : 200,000
    //   s_src   @ 10,200,000 : 6,400,000
    //   s_w     @ 16,600,000 : 6,400,000   (total 23 MB)
    char* ws = (char*)d_ws;
    float* xw      = (float*)(ws + 0);
    int*   counts  = (int*)  (ws + 9600000);
    int*   offsets = (int*)  (ws + 9800000);
    int*   cursor  = (int*)  (ws + 10000000);
    int*   s_src   = (int*)  (ws + 10200000);
    float* s_w     = (float*)(ws + 16600000);

    hipMemsetAsync(counts, 0, (size_t)N_NODES * sizeof(int), stream);

    // 1) xw = features @ weight
    {
        int total = N_NODES * (OUT_CH / 4);
        gemm_xw<<<(total + 255) / 256, 256, 0, stream>>>(features, weight, xw);
    }
    // 2) CSR build
    hist_dst<<<(N_EDGES + 255) / 256, 256, 0, stream>>>(dst, counts);
    scan_offsets<<<1, 1024, 0, stream>>>(counts, offsets, cursor);
    build_perm<<<(N_EDGES + 255) / 256, 256, 0, stream>>>(src, dst, eweights, cursor,
                                                          s_src, s_w);
    // 3) gather-aggregate + bias + log-softmax (one wave per node)
    {
        int waves_per_block = 256 / 64;  // 4
        int blocks = (N_NODES + waves_per_block - 1) / waves_per_block;
        aggregate_lsm<<<blocks, 256, 0, stream>>>(counts, offsets, s_src, s_w,
                                                  xw, bias, out);
    }
}

// Round 4
// 406.413 us; speedup vs baseline: 2.8985x; 1.4338x over previous
//
#include <hip/hip_runtime.h>
#include <math.h>

#define N_NODES 50000
#define N_EDGES 1600000
#define IN_CH   512
#define OUT_CH  48
#define N_TILES (N_NODES / 16)   // 3125 row-tiles, exact

typedef __attribute__((ext_vector_type(8))) short bf16x8;
typedef __attribute__((ext_vector_type(4))) float f32x4;

// fp32 -> bf16 (round-to-nearest-even), branch-free
static __device__ inline short f2bf(float x) {
    union { float f; unsigned u; } in; in.f = x;
    unsigned r = in.u + 0x7fffu + ((in.u >> 16) & 1u);
    return (short)(r >> 16);
}

// ---------------- Kernel 1: xw = features @ weight via bf16 MFMA ----------------
// One wave per 16-row tile. N=48 -> 3 tiles of 16 cols. K=512 -> 16 steps of 32.
// A fragments loaded straight from global (coalesced: wave covers 16 rows x 128B),
// converted to bf16 in-register. B fragments staged once per block in LDS (48 KB).
__global__ __launch_bounds__(256) void gemm_mfma(const float* __restrict__ f,
                                                 const float* __restrict__ w,
                                                 float* __restrict__ xw) {
    __shared__ bf16x8 sB[16 * 3 * 64];   // [s][t][lane], 48 KB

    int tid  = threadIdx.x;
    int lane = tid & 63;
    int wid  = tid >> 6;

    // ---- stage B fragments: w[k][col] -> bf16, frag layout col=lane&15, k=8*(lane>>4)+j
    for (int idx = tid; idx < 16 * 3 * 64 * 8; idx += 256) {
        int j  = idx & 7;
        int ln = (idx >> 3) & 63;
        int st = idx >> 9;           // s*3 + t
        int t  = st % 3;
        int s  = st / 3;
        int k   = s * 32 + ((ln >> 4) << 3) + j;
        int col = t * 16 + (ln & 15);
        reinterpret_cast<short*>(sB)[idx] = f2bf(w[k * OUT_CH + col]);
    }
    __syncthreads();

    int tile = blockIdx.x * 4 + wid;
    if (tile >= N_TILES) return;

    int row = tile * 16 + (lane & 15);
    const float* fp = f + (size_t)row * IN_CH + ((lane >> 4) << 3);

    f32x4 acc0 = {0.f, 0.f, 0.f, 0.f};
    f32x4 acc1 = {0.f, 0.f, 0.f, 0.f};
    f32x4 acc2 = {0.f, 0.f, 0.f, 0.f};

    #pragma unroll 4
    for (int s = 0; s < 16; ++s) {
        float4 a0 = *reinterpret_cast<const float4*>(fp + s * 32);
        float4 a1 = *reinterpret_cast<const float4*>(fp + s * 32 + 4);
        bf16x8 a;
        a[0] = f2bf(a0.x); a[1] = f2bf(a0.y); a[2] = f2bf(a0.z); a[3] = f2bf(a0.w);
        a[4] = f2bf(a1.x); a[5] = f2bf(a1.y); a[6] = f2bf(a1.z); a[7] = f2bf(a1.w);
        bf16x8 b0 = sB[(s * 3 + 0) * 64 + lane];
        bf16x8 b1 = sB[(s * 3 + 1) * 64 + lane];
        bf16x8 b2 = sB[(s * 3 + 2) * 64 + lane];
        acc0 = __builtin_amdgcn_mfma_f32_16x16x32_bf16(a, b0, acc0, 0, 0, 0);
        acc1 = __builtin_amdgcn_mfma_f32_16x16x32_bf16(a, b1, acc1, 0, 0, 0);
        acc2 = __builtin_amdgcn_mfma_f32_16x16x32_bf16(a, b2, acc2, 0, 0, 0);
    }

    // C/D layout (doc-verified): col = lane&15, row = (lane>>4)*4 + reg
    float* orow = xw + (size_t)tile * 16 * OUT_CH;
    int c  = lane & 15;
    int r0 = (lane >> 4) * 4;
    #pragma unroll
    for (int r = 0; r < 4; ++r) {
        orow[(size_t)(r0 + r) * OUT_CH +  0 + c] = acc0[r];
        orow[(size_t)(r0 + r) * OUT_CH + 16 + c] = acc1[r];
        orow[(size_t)(r0 + r) * OUT_CH + 32 + c] = acc2[r];
    }
}

// ---------------- CSR build: histogram of dst ----------------
__global__ void hist_dst(const int* __restrict__ dst, int* __restrict__ counts) {
    int e = blockIdx.x * blockDim.x + threadIdx.x;
    if (e < N_EDGES) atomicAdd(&counts[dst[e]], 1);
}

// ---------------- CSR build: exclusive scan (single block) ----------------
__global__ void scan_offsets(const int* __restrict__ counts,
                             int* __restrict__ offsets,
                             int* __restrict__ cursor) {
    __shared__ int part[1024];
    int t = threadIdx.x;
    const int CH = (N_NODES + 1023) / 1024;  // 49 per thread
    int lo = t * CH;
    int hi = lo + CH; if (hi > N_NODES) hi = N_NODES;

    int s = 0;
    for (int i = lo; i < hi; ++i) s += counts[i];
    part[t] = s;
    __syncthreads();
    for (int d = 1; d < 1024; d <<= 1) {
        int v = (t >= d) ? part[t - d] : 0;
        __syncthreads();
        part[t] += v;
        __syncthreads();
    }
    int run = (t == 0) ? 0 : part[t - 1];
    for (int i = lo; i < hi; ++i) {
        offsets[i] = run;
        cursor[i]  = run;
        run += counts[i];
    }
}

// ---------------- CSR build: permute (src, w) into dst-buckets, packed 8B ----------------
__global__ void build_perm(const int* __restrict__ src, const int* __restrict__ dst,
                           const float* __restrict__ ew, int* __restrict__ cursor,
                           int2* __restrict__ epack) {
    int e = blockIdx.x * blockDim.x + threadIdx.x;
    if (e >= N_EDGES) return;
    int d = dst[e];
    int pos = atomicAdd(&cursor[d], 1);
    int2 p; p.x = src[e]; p.y = __float_as_int(ew[e]);
    epack[pos] = p;
}

// ---------------- Fused gather-aggregate + bias + log-softmax ----------------
// One wave per destination node; lane = output channel (48 active).
__global__ void aggregate_lsm(const int* __restrict__ counts,
                              const int* __restrict__ offsets,
                              const int2* __restrict__ epack,
                              const float* __restrict__ xw,
                              const float* __restrict__ bias,
                              float* __restrict__ out) {
    int node = (blockIdx.x * blockDim.x + threadIdx.x) >> 6;
    int lane = threadIdx.x & 63;
    if (node >= N_NODES) return;

    int off = offsets[node];
    int cnt = counts[node];

    float acc = 0.f;
    if (lane < OUT_CH) {
        int k = 0;
        for (; k + 4 <= cnt; k += 4) {
            int2 e0 = epack[off + k + 0];
            int2 e1 = epack[off + k + 1];
            int2 e2 = epack[off + k + 2];
            int2 e3 = epack[off + k + 3];
            float x0 = xw[(size_t)e0.x * OUT_CH + lane];
            float x1 = xw[(size_t)e1.x * OUT_CH + lane];
            float x2 = xw[(size_t)e2.x * OUT_CH + lane];
            float x3 = xw[(size_t)e3.x * OUT_CH + lane];
            acc = fmaf(__int_as_float(e0.y), x0, acc);
            acc = fmaf(__int_as_float(e1.y), x1, acc);
            acc = fmaf(__int_as_float(e2.y), x2, acc);
            acc = fmaf(__int_as_float(e3.y), x3, acc);
        }
        for (; k < cnt; ++k) {
            int2 e0 = epack[off + k];
            acc = fmaf(__int_as_float(e0.y), xw[(size_t)e0.x * OUT_CH + lane], acc);
        }
        acc += bias[lane];
    }

    float z = (lane < OUT_CH) ? acc : -INFINITY;
    float m = z;
    #pragma unroll
    for (int d = 32; d >= 1; d >>= 1) m = fmaxf(m, __shfl_xor(m, d));
    float e = (lane < OUT_CH) ? expf(z - m) : 0.f;
    float s = e;
    #pragma unroll
    for (int d = 32; d >= 1; d >>= 1) s += __shfl_xor(s, d);
    float lse = m + logf(s);

    if (lane < OUT_CH) out[(size_t)node * OUT_CH + lane] = z - lse;
}

extern "C" void kernel_launch(void* const* d_in, const int* in_sizes, int n_in,
                              void* d_out, int out_size, void* d_ws, size_t ws_size,
                              hipStream_t stream) {
    const int*   edge_index = (const int*)d_in[0];
    const float* features   = (const float*)d_in[1];
    const float* eweights   = (const float*)d_in[2];
    const float* weight     = (const float*)d_in[3];
    const float* bias       = (const float*)d_in[4];

    const int* src = edge_index;            // edge_index[0, :]
    const int* dst = edge_index + N_EDGES;  // edge_index[1, :]

    float* out = (float*)d_out;

    // Workspace layout (bytes):
    //   xw      @ 0          : 50000*48*4 = 9,600,000
    //   counts  @ 9,600,000  : 200,000
    //   offsets @ 9,800,000  : 200,000
    //   cursor  @ 10,000,000 : 200,000
    //   epack   @ 10,200,000 : 12,800,000   (total 23 MB)
    char* ws = (char*)d_ws;
    float* xw      = (float*)(ws + 0);
    int*   counts  = (int*)  (ws + 9600000);
    int*   offsets = (int*)  (ws + 9800000);
    int*   cursor  = (int*)  (ws + 10000000);
    int2*  epack   = (int2*) (ws + 10200000);

    hipMemsetAsync(counts, 0, (size_t)N_NODES * sizeof(int), stream);

    // 1) xw = features @ weight  (bf16 MFMA)
    {
        int blocks = (N_TILES + 3) / 4;   // 4 waves (row-tiles) per 256-thread block
        gemm_mfma<<<blocks, 256, 0, stream>>>(features, weight, xw);
    }
    // 2) CSR build
    hist_dst<<<(N_EDGES + 255) / 256, 256, 0, stream>>>(dst, counts);
    scan_offsets<<<1, 1024, 0, stream>>>(counts, offsets, cursor);
    build_perm<<<(N_EDGES + 255) / 256, 256, 0, stream>>>(src, dst, eweights, cursor, epack);
    // 3) gather-aggregate + bias + log-softmax (one wave per node)
    {
        int waves_per_block = 256 / 64;
        int blocks = (N_NODES + waves_per_block - 1) / waves_per_block;
        aggregate_lsm<<<blocks, 256, 0, stream>>>(counts, offsets, epack, xw, bias, out);
    }
}